// Round 7
// baseline (142.191 us; speedup 1.0000x reference)
//
#include <hip/hip_runtime.h>
#include <hip/hip_bf16.h>

#define B_ 8
#define D_ 128
#define S_ 4096

typedef short short8 __attribute__((ext_vector_type(8)));
typedef float f32x4  __attribute__((ext_vector_type(4)));
typedef float f32x16 __attribute__((ext_vector_type(16)));
typedef unsigned int uint;
typedef uint uint4v __attribute__((ext_vector_type(4)));

#define EXP2F(x) exp2f(x)

__device__ __forceinline__ short f2bf(float f) {
    __hip_bfloat16 h = __float2bfloat16(f);
    return *reinterpret_cast<short*>(&h);
}

// pack two f32 -> one u32 of 2 bf16 (elem0 = lo word)
__device__ __forceinline__ uint cvtpk(float lo, float hi) {
    uint r;
    asm("v_cvt_pk_bf16_f32 %0, %1, %2" : "=v"(r) : "v"(lo), "v"(hi));
    return r;
}

// async global->LDS DMA, 16B/lane; LDS dest = wave-uniform base + lane*16
__device__ __forceinline__ void gload16(const void* g, void* l) {
    __builtin_amdgcn_global_load_lds(
        (const __attribute__((address_space(1))) void*)g,
        (__attribute__((address_space(3))) void*)l, 16, 0, 0);
}

// ---------------------------------------------------------------------------
// Kernel 0: pack Wq/Wk/Wv into bf16 MFMA fragments (16x16x32 layout for qkv).
// ---------------------------------------------------------------------------
__global__ __launch_bounds__(256) void wpack_kernel(
    const float* __restrict__ Wq, const float* __restrict__ Wk,
    const float* __restrict__ Wv, short* __restrict__ Wf)
{
    int g = blockIdx.x * 256 + threadIdx.x;      // 0..6143
    int lane = g & 63, kc = (g >> 6) & 3, n = (g >> 8) & 7, wm = g >> 11;
    const float* W = (wm == 0) ? Wq : (wm == 1) ? Wk : Wv;
    int row = n * 16 + (lane & 15);
    int col = kc * 32 + (lane >> 4) * 8;
    short8 o;
    #pragma unroll
    for (int j = 0; j < 8; ++j) o[j] = f2bf(W[row * 128 + col + j]);
    *((short8*)Wf + g) = o;
}

// ---------------------------------------------------------------------------
// Kernel 1: QKV projection via bf16 MFMA (16x16x32), unchanged.
// Q: (B,S,D) bf16 scaled by log2(e)/sqrt(D). K: (B,S,D). V: (B,D,S).
// ---------------------------------------------------------------------------
__global__ __launch_bounds__(256) void qkv_kernel(
    const float* __restrict__ x, const short* __restrict__ Wf,
    const float* __restrict__ bq, const float* __restrict__ bk,
    const float* __restrict__ bv,
    short* __restrict__ Qo, short* __restrict__ Ko, short* __restrict__ Vo)
{
    __shared__ float xt[64 * 132];
    const int b  = blockIdx.y;
    const int s0 = blockIdx.x * 64;
    const int t  = threadIdx.x;
    const int w    = t >> 6;
    const int lane = t & 63;
    const int lr   = lane & 15;
    const int lg   = lane >> 4;

    const float* xb = x + (size_t)b * D_ * S_;
    #pragma unroll
    for (int it = 0; it < 32; ++it) {
        int d = it * 4 + (t >> 6);
        int s = t & 63;
        xt[s * 132 + d] = xb[(size_t)d * S_ + s0 + s];
    }
    __syncthreads();

    short8 xtf[4];
    {
        const float* base = &xt[(w * 16 + lr) * 132 + lg * 8];
        #pragma unroll
        for (int kc = 0; kc < 4; ++kc) {
            float4 a = *(const float4*)(base + kc * 32);
            float4 c = *(const float4*)(base + kc * 32 + 4);
            short8 f;
            f[0] = f2bf(a.x); f[1] = f2bf(a.y); f[2] = f2bf(a.z); f[3] = f2bf(a.w);
            f[4] = f2bf(c.x); f[5] = f2bf(c.y); f[6] = f2bf(c.z); f[7] = f2bf(c.w);
            xtf[kc] = f;
        }
    }

    const float qs = 0.08838834764831845f * 1.4426950408889634f;
    const short8* W8 = (const short8*)Wf;
    const size_t bSD = (size_t)b * S_ * D_;
    const size_t bDS = (size_t)b * D_ * S_;

    #pragma unroll
    for (int n = 0; n < 8; ++n) {
        f32x4 aq = (f32x4){0.f, 0.f, 0.f, 0.f};
        f32x4 ak = (f32x4){0.f, 0.f, 0.f, 0.f};
        f32x4 av = (f32x4){0.f, 0.f, 0.f, 0.f};
        #pragma unroll
        for (int kc = 0; kc < 4; ++kc) {
            short8 wq = W8[(      n * 4 + kc) * 64 + lane];
            short8 wk = W8[(32  + n * 4 + kc) * 64 + lane];
            short8 wv = W8[(64  + n * 4 + kc) * 64 + lane];
            aq = __builtin_amdgcn_mfma_f32_16x16x32_bf16(xtf[kc], wq, aq, 0, 0, 0);
            ak = __builtin_amdgcn_mfma_f32_16x16x32_bf16(xtf[kc], wk, ak, 0, 0, 0);
            av = __builtin_amdgcn_mfma_f32_16x16x32_bf16(wv, xtf[kc], av, 0, 0, 0);
        }
        int e = n * 16 + lr;
        float bqe = bq[e], bke = bk[e];
        #pragma unroll
        for (int r = 0; r < 4; ++r) {
            size_t off = (bSD + (size_t)(s0 + w * 16 + lg * 4 + r) * D_) + e;
            Qo[off] = f2bf((aq[r] + bqe) * qs);
            Ko[off] = f2bf(ak[r] + bke);
        }
        #pragma unroll
        for (int r = 0; r < 4; ++r) {
            int ev = n * 16 + lg * 4 + r;
            Vo[bDS + (size_t)ev * S_ + s0 + w * 16 + lr] = f2bf(av[r] + bv[ev]);
        }
    }
}

// ---------------------------------------------------------------------------
// Kernel 2: flash attention, QBLK=64 register-blocked (LDS traffic halved).
// 256 blocks x 256 threads = 4 waves = 2 q-strips (64 q) x 2 kv-halves.
// __launch_bounds__(256,1): 1 wave/SIMD, 512-VGPR budget -> o[2][4]+acc[2][2]
// +qf[2][8] (~320 regs) fit WITHOUT spill. Each K fragment ds_read feeds the
// MFMAs of BOTH q-sub-blocks; each V fragment feeds both o banks -> LDS reads
// per MFMA-FLOP are HALVED vs QBLK=32 (R0..R6 were LDS-pipe-bound: 8 MB/CU
// reads at ~85 B/cyc ~= 60us, barrier-convoyed with VALU/MFMA phases).
// K/V staged by the half's 2 waves via global_load_lds, double-buffered,
// 1 barrier/tile. All swizzles/index math identical to the verified R0.
// C/D layout (m74/m101): col=lane&31, row=(reg&3)+8*(reg>>2)+4*(lane>>5).
// ---------------------------------------------------------------------------
__global__ __launch_bounds__(256, 1) void attn_kernel(
    const short* __restrict__ Q, const short* __restrict__ K,
    const short* __restrict__ Vt, const float* __restrict__ x,
    float* __restrict__ out)
{
    extern __shared__ __align__(16) char smem[];   // 132096 B
    const int lin = blockIdx.x;
    const int b   = lin & 7;            // XCD swizzle: one b per XCD
    const int q0  = (lin >> 3) * 128;
    const int tid  = threadIdx.x;
    const int w    = tid >> 6;          // 0..3
    const int lane = tid & 63;
    const int q    = lane & 31;         // this lane's q column (within sub-block)
    const int hi   = lane >> 5;
    const int half = w >> 1;            // KV half: tiles of rows half*2048..
    const int ww   = w & 1;             // q strip (64 q): q0 + ww*64 ..

    const size_t bSD = (size_t)b * S_ * D_;

    // Q fragments: qf{0,1}[c][j] = Q[q0+ww*64+qb*32+q][c*16 + hi*8 + j]
    short8 qf0[8], qf1[8];
    {
        const short* Qr0 = Q + bSD + (size_t)(q0 + ww * 64 + q) * D_ + hi * 8;
        const short* Qr1 = Qr0 + 32 * D_;
        #pragma unroll
        for (int c = 0; c < 8; ++c) {
            qf0[c] = *(const short8*)(Qr0 + c * 16);
            qf1[c] = *(const short8*)(Qr1 + c * 16);
        }
    }

    f32x16 o0[4], o1[4];
    #pragma unroll
    for (int dt = 0; dt < 4; ++dt)
        #pragma unroll
        for (int i = 0; i < 16; ++i) { o0[dt][i] = 0.f; o1[dt][i] = 0.f; }
    float m0 = -1e30f, l0 = 0.f, m1 = -1e30f, l1 = 0.f;

    const short* Kb = K + bSD;
    const short* Vb = Vt + (size_t)b * D_ * S_;
    const int kvbase = half * 2048;

    // Per-half LDS: K dbuf 2x16KB then V dbuf 2x16KB (64KB per half).
    char* const Kbase = smem + half * 65536;
    char* const Vbase = Kbase + 32768;

    // DMA staging (linear LDS dest; global src pre-swizzled: phys 16B-chunk c
    // of row r holds logical chunk c^(r&7)). Each of the half's 2 waves
    // stages 8KB of K and 8KB of V (8 chunks each).
    auto stageK = [&](int kt, int buf) {
        const short* Kg = Kb + (size_t)(kvbase + kt * 64) * D_;
        char* Kd = Kbase + buf * 16384;
        #pragma unroll
        for (int i = 0; i < 8; ++i) {
            int ki = ww * 8 + i;                 // 1KB chunk: rows 4ki..4ki+3
            int r  = ki * 4 + (lane >> 4);
            gload16(Kg + r * D_ + (((lane & 15) ^ (r & 7)) * 8), Kd + ki * 1024);
        }
    };
    auto stageV = [&](int kt, int buf) {
        const short* Vg = Vb + kvbase + kt * 64;
        char* Vd = Vbase + buf * 16384;
        #pragma unroll
        for (int i = 0; i < 8; ++i) {
            int vi = ww * 8 + i;                 // 1KB chunk: rows 8vi..8vi+7
            int r  = vi * 8 + (lane >> 3);
            gload16(Vg + (size_t)r * S_ + (((lane & 7) ^ (lane >> 3)) * 8),
                    Vd + vi * 1024);
        }
    };

    // Per-qb softmax: tile max, T13 gate+rescale, exp, sum, pack pf[0..3].
    auto smqb = [&](f32x16& A0, f32x16& A1, float& m, float& lsum,
                    f32x16* o, short8* pf) {
        float x0 = fmaxf(fmaxf(A0[0],  A0[1]),  fmaxf(A0[2],  A0[3]));
        float x1 = fmaxf(fmaxf(A0[4],  A0[5]),  fmaxf(A0[6],  A0[7]));
        float x2 = fmaxf(fmaxf(A0[8],  A0[9]),  fmaxf(A0[10], A0[11]));
        float x3 = fmaxf(fmaxf(A0[12], A0[13]), fmaxf(A0[14], A0[15]));
        float x4 = fmaxf(fmaxf(A1[0],  A1[1]),  fmaxf(A1[2],  A1[3]));
        float x5 = fmaxf(fmaxf(A1[4],  A1[5]),  fmaxf(A1[6],  A1[7]));
        float x6 = fmaxf(fmaxf(A1[8],  A1[9]),  fmaxf(A1[10], A1[11]));
        float x7 = fmaxf(fmaxf(A1[12], A1[13]), fmaxf(A1[14], A1[15]));
        float tm = fmaxf(fmaxf(fmaxf(x0, x1), fmaxf(x2, x3)),
                         fmaxf(fmaxf(x4, x5), fmaxf(x6, x7)));
        tm = fmaxf(tm, __shfl_xor(tm, 32));
        if (!__all(tm <= m + 8.f)) {
            float mn   = fmaxf(m, tm);
            float corr = EXP2F(m - mn);
            m = mn; lsum *= corr;
            #pragma unroll
            for (int dt = 0; dt < 4; ++dt)
                #pragma unroll
                for (int r = 0; r < 16; ++r) o[dt][r] *= corr;
        }
        #pragma unroll
        for (int r = 0; r < 16; ++r) A0[r] = EXP2F(A0[r] - m);
        #pragma unroll
        for (int r = 0; r < 16; ++r) A1[r] = EXP2F(A1[r] - m);
        float s0 = ((A0[0]+A0[1])+(A0[2]+A0[3])) + ((A0[4]+A0[5])+(A0[6]+A0[7]));
        float s1 = ((A0[8]+A0[9])+(A0[10]+A0[11])) + ((A0[12]+A0[13])+(A0[14]+A0[15]));
        float s2 = ((A1[0]+A1[1])+(A1[2]+A1[3])) + ((A1[4]+A1[5])+(A1[6]+A1[7]));
        float s3 = ((A1[8]+A1[9])+(A1[10]+A1[11])) + ((A1[12]+A1[13])+(A1[14]+A1[15]));
        float ps = (s0 + s1) + (s2 + s3);
        ps += __shfl_xor(ps, 32);
        lsum += ps;

        // P -> bf16 PV B-fragments (distinct SSA defs -> permlane safe)
        #pragma unroll
        for (int kc = 0; kc < 4; ++kc) {
            const f32x16& a = (kc < 2) ? A0 : A1;
            int c1 = (kc & 1) * 8;
            uint W0 = cvtpk(a[c1 + 0], a[c1 + 1]);
            uint W1 = cvtpk(a[c1 + 2], a[c1 + 3]);
            uint W2 = cvtpk(a[c1 + 4], a[c1 + 5]);
            uint W3 = cvtpk(a[c1 + 6], a[c1 + 7]);
            asm("v_permlane32_swap_b32 %0, %1" : "+v"(W0), "+v"(W2));
            asm("v_permlane32_swap_b32 %0, %1" : "+v"(W1), "+v"(W3));
            uint4v pw;
            pw.x = W0; pw.y = W1; pw.z = W2; pw.w = W3;
            pf[kc] = *reinterpret_cast<short8*>(&pw);
        }
    };

    auto tilebody = [&](int buf) {
        const char* Kh = Kbase + buf * 16384;
        const char* Vh = Vbase + buf * 16384;

        // ---- S^T = K Q^T, both q-sub-blocks share each K fragment ----
        f32x16 a00, a01, a10, a11;     // [qb][n]
        #pragma unroll
        for (int i = 0; i < 16; ++i) { a00[i]=0.f; a01[i]=0.f; a10[i]=0.f; a11[i]=0.f; }
        #pragma unroll
        for (int c = 0; c < 8; ++c) {
            int co = ((c * 2 + hi) ^ (q & 7)) * 16;
            short8 k0 = *(const short8*)(Kh + q * 256 + co);
            short8 k1 = *(const short8*)(Kh + (32 + q) * 256 + co);
            a00 = __builtin_amdgcn_mfma_f32_32x32x16_bf16(k0, qf0[c], a00, 0, 0, 0);
            a01 = __builtin_amdgcn_mfma_f32_32x32x16_bf16(k1, qf0[c], a01, 0, 0, 0);
            a10 = __builtin_amdgcn_mfma_f32_32x32x16_bf16(k0, qf1[c], a10, 0, 0, 0);
            a11 = __builtin_amdgcn_mfma_f32_32x32x16_bf16(k1, qf1[c], a11, 0, 0, 0);
        }

        // ---- online softmax per q-sub-block ----
        short8 pf0[4], pf1[4];
        smqb(a00, a01, m0, l0, o0, pf0);
        smqb(a10, a11, m1, l1, o1, pf1);

        // ---- O^T += V^T P^T, both q-sub-blocks share each V fragment ----
        #pragma unroll
        for (int kc = 0; kc < 4; ++kc)
            #pragma unroll
            for (int dt = 0; dt < 4; ++dt) {
                int row = dt * 32 + q;
                short8 vf = *(const short8*)(Vh + row * 128
                              + (((kc * 2 + hi) ^ (q & 7)) * 16));
                o0[dt] = __builtin_amdgcn_mfma_f32_32x32x16_bf16(vf, pf0[kc], o0[dt], 0, 0, 0);
                o1[dt] = __builtin_amdgcn_mfma_f32_32x32x16_bf16(vf, pf1[kc], o1[dt], 0, 0, 0);
            }
    };

    // Prologue
    stageK(0, 0); stageV(0, 0);
    __syncthreads();
    int cur = 0;

    for (int kt = 0; kt < 31; ++kt) {
        stageK(kt + 1, cur ^ 1);
        stageV(kt + 1, cur ^ 1);
        tilebody(cur);
        __syncthreads();   // half's reads of buf[cur] done + DMA drained
        cur ^= 1;
    }
    tilebody(cur);         // tile 31, no stage

    // ---- merge halves through LDS, residual-fused transposed writeout ----
    __syncthreads();
    float2* ml = (float2*)(smem + 131072);
    if (half == 1) {
        float* obuf = (float*)(smem + ww * 32768);   // strip's 32KB (dead K/V)
        #pragma unroll
        for (int dt = 0; dt < 4; ++dt)
            #pragma unroll
            for (int r = 0; r < 16; ++r) {
                int dl = dt * 32 + (r & 3) + 8 * (r >> 2) + 4 * hi;
                obuf[dl * 64 + q]      = o0[dt][r];
                obuf[dl * 64 + 32 + q] = o1[dt][r];
            }
        if (hi == 0) {
            float2 v0; v0.x = m0; v0.y = l0;
            float2 v1; v1.x = m1; v1.y = l1;
            ml[ww * 64 + q]      = v0;
            ml[ww * 64 + 32 + q] = v1;
        }
    }
    __syncthreads();
    if (half == 0) {
        const float* obuf = (const float*)(smem + ww * 32768);
        const float* xb = x   + (size_t)b * D_ * S_;
        float*       ob = out + (size_t)b * D_ * S_;

        float2 p0 = ml[ww * 64 + q];
        float2 p1 = ml[ww * 64 + 32 + q];
        // qb = 0
        {
            float M  = fmaxf(m0, p0.x);
            float c1 = EXP2F(m0 - M), c2 = EXP2F(p0.x - M);
            float inv = 1.0f / (l0 * c1 + p0.y * c2);
            int s = q0 + ww * 64 + q;
            #pragma unroll
            for (int dt = 0; dt < 4; ++dt)
                #pragma unroll
                for (int r = 0; r < 16; ++r) {
                    int dl = dt * 32 + (r & 3) + 8 * (r >> 2) + 4 * hi;
                    float val = (o0[dt][r] * c1 + obuf[dl * 64 + q] * c2) * inv;
                    size_t g = (size_t)dl * S_ + s;
                    ob[g] = xb[g] + val;
                }
        }
        // qb = 1
        {
            float M  = fmaxf(m1, p1.x);
            float c1 = EXP2F(m1 - M), c2 = EXP2F(p1.x - M);
            float inv = 1.0f / (l1 * c1 + p1.y * c2);
            int s = q0 + ww * 64 + 32 + q;
            #pragma unroll
            for (int dt = 0; dt < 4; ++dt)
                #pragma unroll
                for (int r = 0; r < 16; ++r) {
                    int dl = dt * 32 + (r & 3) + 8 * (r >> 2) + 4 * hi;
                    float val = (o1[dt][r] * c1 + obuf[dl * 64 + 32 + q] * c2) * inv;
                    size_t g = (size_t)dl * S_ + s;
                    ob[g] = xb[g] + val;
                }
        }
    }
}

extern "C" void kernel_launch(void* const* d_in, const int* in_sizes, int n_in,
                              void* d_out, int out_size, void* d_ws, size_t ws_size,
                              hipStream_t stream) {
    const float* x  = (const float*)d_in[0];
    const float* Wq = (const float*)d_in[1];
    const float* bq = (const float*)d_in[2];
    const float* Wk = (const float*)d_in[3];
    const float* bk = (const float*)d_in[4];
    const float* Wv = (const float*)d_in[5];
    const float* bv = (const float*)d_in[6];
    float* out = (float*)d_out;

    size_t n = (size_t)B_ * S_ * D_;
    short* Qw = (short*)d_ws;
    short* Kw = Qw + n;
    short* Vw = Kw + n;
    short* Wf = (short*)d_out;   // scratch at head of d_out; fully overwritten

    wpack_kernel<<<24, 256, 0, stream>>>(Wq, Wk, Wv, Wf);

    dim3 grid(S_ / 64, B_);
    qkv_kernel<<<grid, 256, 0, stream>>>(x, Wf, bq, bk, bv, Qw, Kw, Vw);

    int smemB = 132096;
    (void)hipFuncSetAttribute((const void*)attn_kernel,
                              hipFuncAttributeMaxDynamicSharedMemorySize, smemB);
    attn_kernel<<<256, 256, smemB, stream>>>(Qw, Kw, Vw, x, out);
}

// Round 8
// 121.022 us; speedup vs baseline: 1.1749x; 1.1749x over previous
//
#include <hip/hip_runtime.h>
#include <hip/hip_bf16.h>

#define B_ 8
#define D_ 128
#define S_ 4096

typedef short short8 __attribute__((ext_vector_type(8)));
typedef float f32x4  __attribute__((ext_vector_type(4)));
typedef float f32x16 __attribute__((ext_vector_type(16)));
typedef unsigned int uint;
typedef uint uint4v __attribute__((ext_vector_type(4)));

#define EXP2F(x) exp2f(x)

__device__ __forceinline__ short f2bf(float f) {
    __hip_bfloat16 h = __float2bfloat16(f);
    return *reinterpret_cast<short*>(&h);
}

// pack two f32 -> one u32 of 2 bf16 (elem0 = lo word)
__device__ __forceinline__ uint cvtpk(float lo, float hi) {
    uint r;
    asm("v_cvt_pk_bf16_f32 %0, %1, %2" : "=v"(r) : "v"(lo), "v"(hi));
    return r;
}

// async global->LDS DMA, 16B/lane; LDS dest = wave-uniform base + lane*16
__device__ __forceinline__ void gload16(const void* g, void* l) {
    __builtin_amdgcn_global_load_lds(
        (const __attribute__((address_space(1))) void*)g,
        (__attribute__((address_space(3))) void*)l, 16, 0, 0);
}

// ---------------------------------------------------------------------------
// Kernel 0: pack Wq/Wk/Wv into bf16 MFMA fragments (16x16x32 layout for qkv).
// ---------------------------------------------------------------------------
__global__ __launch_bounds__(256) void wpack_kernel(
    const float* __restrict__ Wq, const float* __restrict__ Wk,
    const float* __restrict__ Wv, short* __restrict__ Wf)
{
    int g = blockIdx.x * 256 + threadIdx.x;      // 0..6143
    int lane = g & 63, kc = (g >> 6) & 3, n = (g >> 8) & 7, wm = g >> 11;
    const float* W = (wm == 0) ? Wq : (wm == 1) ? Wk : Wv;
    int row = n * 16 + (lane & 15);
    int col = kc * 32 + (lane >> 4) * 8;
    short8 o;
    #pragma unroll
    for (int j = 0; j < 8; ++j) o[j] = f2bf(W[row * 128 + col + j]);
    *((short8*)Wf + g) = o;
}

// ---------------------------------------------------------------------------
// Kernel 1: QKV projection via bf16 MFMA (16x16x32), unchanged.
// Q: (B,S,D) bf16 scaled by log2(e)/sqrt(D). K: (B,S,D). V: (B,D,S).
// ---------------------------------------------------------------------------
__global__ __launch_bounds__(256) void qkv_kernel(
    const float* __restrict__ x, const short* __restrict__ Wf,
    const float* __restrict__ bq, const float* __restrict__ bk,
    const float* __restrict__ bv,
    short* __restrict__ Qo, short* __restrict__ Ko, short* __restrict__ Vo)
{
    __shared__ float xt[64 * 132];
    const int b  = blockIdx.y;
    const int s0 = blockIdx.x * 64;
    const int t  = threadIdx.x;
    const int w    = t >> 6;
    const int lane = t & 63;
    const int lr   = lane & 15;
    const int lg   = lane >> 4;

    const float* xb = x + (size_t)b * D_ * S_;
    #pragma unroll
    for (int it = 0; it < 32; ++it) {
        int d = it * 4 + (t >> 6);
        int s = t & 63;
        xt[s * 132 + d] = xb[(size_t)d * S_ + s0 + s];
    }
    __syncthreads();

    short8 xtf[4];
    {
        const float* base = &xt[(w * 16 + lr) * 132 + lg * 8];
        #pragma unroll
        for (int kc = 0; kc < 4; ++kc) {
            float4 a = *(const float4*)(base + kc * 32);
            float4 c = *(const float4*)(base + kc * 32 + 4);
            short8 f;
            f[0] = f2bf(a.x); f[1] = f2bf(a.y); f[2] = f2bf(a.z); f[3] = f2bf(a.w);
            f[4] = f2bf(c.x); f[5] = f2bf(c.y); f[6] = f2bf(c.z); f[7] = f2bf(c.w);
            xtf[kc] = f;
        }
    }

    const float qs = 0.08838834764831845f * 1.4426950408889634f;
    const short8* W8 = (const short8*)Wf;
    const size_t bSD = (size_t)b * S_ * D_;
    const size_t bDS = (size_t)b * D_ * S_;

    #pragma unroll
    for (int n = 0; n < 8; ++n) {
        f32x4 aq = (f32x4){0.f, 0.f, 0.f, 0.f};
        f32x4 ak = (f32x4){0.f, 0.f, 0.f, 0.f};
        f32x4 av = (f32x4){0.f, 0.f, 0.f, 0.f};
        #pragma unroll
        for (int kc = 0; kc < 4; ++kc) {
            short8 wq = W8[(      n * 4 + kc) * 64 + lane];
            short8 wk = W8[(32  + n * 4 + kc) * 64 + lane];
            short8 wv = W8[(64  + n * 4 + kc) * 64 + lane];
            aq = __builtin_amdgcn_mfma_f32_16x16x32_bf16(xtf[kc], wq, aq, 0, 0, 0);
            ak = __builtin_amdgcn_mfma_f32_16x16x32_bf16(xtf[kc], wk, ak, 0, 0, 0);
            av = __builtin_amdgcn_mfma_f32_16x16x32_bf16(wv, xtf[kc], av, 0, 0, 0);
        }
        int e = n * 16 + lr;
        float bqe = bq[e], bke = bk[e];
        #pragma unroll
        for (int r = 0; r < 4; ++r) {
            size_t off = (bSD + (size_t)(s0 + w * 16 + lg * 4 + r) * D_) + e;
            Qo[off] = f2bf((aq[r] + bqe) * qs);
            Ko[off] = f2bf(ak[r] + bke);
        }
        #pragma unroll
        for (int r = 0; r < 4; ++r) {
            int ev = n * 16 + lg * 4 + r;
            Vo[bDS + (size_t)ev * S_ + s0 + w * 16 + lr] = f2bf(av[r] + bv[ev]);
        }
    }
}

// ---------------------------------------------------------------------------
// Kernel 2: flash attention = the verified R0 structure (512 thr, 2 KV-halves
// x 4 q-strips, 64-kv tiles, K+V DMA-staged, double-buffered, 1 barrier/tile)
// + MANUAL DEPTH-2 PREFETCH of all LDS fragment reads.
// Diagnosis (R7, 1-wave/SIMD isolation): ~120cyc ds_read_b128 latency was
// serially exposed at EVERY fragment read (compiler can't hoist under
// register pressure) -> ~3900 cyc/wave/tile of pure LDS-latency stall, the
// dominant term of the 9075-cyc tile period. Fix: rotate reads through
// parity-indexed 2-slot register buffers so each read is issued one MFMA
// pair (~64cyc) ahead of its use; exposure drops to ~56cyc per pair.
// All indices/swizzles identical to R0. Static indices only (rule #20).
// C/D layout (m74/m101): col=lane&31, row=(reg&3)+8*(reg>>2)+4*(lane>>5).
// ---------------------------------------------------------------------------
__global__ __launch_bounds__(512, 2) void attn_kernel(
    const short* __restrict__ Q, const short* __restrict__ K,
    const short* __restrict__ Vt, const float* __restrict__ x,
    float* __restrict__ out)
{
    extern __shared__ __align__(16) char smem[];   // 131072 B
    const int lin = blockIdx.x;
    const int b   = lin & 7;            // XCD swizzle: one b per XCD
    const int q0  = (lin >> 3) * 128;
    const int tid  = threadIdx.x;
    const int w    = tid >> 6;
    const int lane = tid & 63;
    const int q    = lane & 31;         // this lane's q column
    const int hi   = lane >> 5;
    const int half = w >> 2;            // KV half: kt 0..31 -> rows half*2048..
    const int ww   = w & 3;             // q strip (q0 + ww*32 ..)

    const size_t bSD = (size_t)b * S_ * D_;

    // Q fragments: qf[c][j] = Q[q0+ww*32+q][c*16 + hi*8 + j]
    short8 qf[8];
    {
        const short* Qrow = Q + bSD + (size_t)(q0 + ww * 32 + q) * D_ + hi * 8;
        #pragma unroll
        for (int c = 0; c < 8; ++c)
            qf[c] = *(const short8*)(Qrow + c * 16);
    }

    f32x16 o[4];
    #pragma unroll
    for (int dt = 0; dt < 4; ++dt)
        #pragma unroll
        for (int i = 0; i < 16; ++i) o[dt][i] = 0.f;
    float m = -1e30f, lsum = 0.f;

    const short* Kb = K + bSD;
    const short* Vb = Vt + (size_t)b * D_ * S_;
    const int ktbase = half * 32;

    // DMA-stage one 64-kv tile of this wave's half into buffer `buf`.
    // LDS dest linear; global src pre-swizzled (phys 16B-chunk c of row r
    // holds logical chunk c^(r&7)).
    auto stage = [&](int kt, int buf) {
        const short* Kg = Kb + (size_t)(ktbase + kt) * 64 * D_;
        const short* Vg = Vb + (size_t)(ktbase + kt) * 64;
        char* Kd = smem + buf * 65536 + half * 32768;
        char* Vd = Kd + 16384;
        #pragma unroll
        for (int i = 0; i < 4; ++i) {
            int ki = ww * 4 + i;                 // 1KB chunk: rows 4ki..4ki+3
            int r  = ki * 4 + (lane >> 4);
            gload16(Kg + r * D_ + (((lane & 15) ^ (r & 7)) * 8), Kd + ki * 1024);
        }
        #pragma unroll
        for (int i = 0; i < 4; ++i) {
            int vi = ww * 4 + i;                 // 1KB chunk: rows 8vi..8vi+7
            int r  = vi * 8 + (lane >> 3);
            gload16(Vg + (size_t)r * S_ + (((lane & 7) ^ (lane >> 3)) * 8),
                    Vd + vi * 1024);
        }
    };

    stage(0, 0);
    __syncthreads();                 // drains vmcnt -> buf0 ready
    int cur = 0;

    for (int kt = 0; kt < 32; ++kt) {
        if (kt + 1 < 32) stage(kt + 1, cur ^ 1);   // DMA overlaps compute

        const char* Kh = smem + cur * 65536 + half * 32768;
        const char* Vh = Kh + 16384;

        // ---- S^T = K Q^T : acc[n][r] = S[k = n*32+(r&3)+8*(r>>2)+4*hi][q] --
        // Depth-2 prefetch: reads for c+1 issued before the MFMAs of c.
        f32x16 acc0, acc1;
        #pragma unroll
        for (int i = 0; i < 16; ++i) { acc0[i] = 0.f; acc1[i] = 0.f; }
        short8 kf[2][2];
        {
            int co = ((0 * 2 + hi) ^ (q & 7)) * 16;
            kf[0][0] = *(const short8*)(Kh + q * 256 + co);
            kf[0][1] = *(const short8*)(Kh + (32 + q) * 256 + co);
        }
        __builtin_amdgcn_s_setprio(1);
        #pragma unroll
        for (int c = 0; c < 8; ++c) {
            if (c < 7) {
                int co = (((c + 1) * 2 + hi) ^ (q & 7)) * 16;
                kf[(c + 1) & 1][0] = *(const short8*)(Kh + q * 256 + co);
                kf[(c + 1) & 1][1] = *(const short8*)(Kh + (32 + q) * 256 + co);
            }
            acc0 = __builtin_amdgcn_mfma_f32_32x32x16_bf16(kf[c & 1][0], qf[c], acc0, 0, 0, 0);
            acc1 = __builtin_amdgcn_mfma_f32_32x32x16_bf16(kf[c & 1][1], qf[c], acc1, 0, 0, 0);
        }
        __builtin_amdgcn_s_setprio(0);

        // ---- lane-local online softmax (exp2 domain), defer-max (T13) ----
        float t0 = fmaxf(acc0[0],  acc0[1]),  t1 = fmaxf(acc0[2],  acc0[3]);
        float t2 = fmaxf(acc0[4],  acc0[5]),  t3 = fmaxf(acc0[6],  acc0[7]);
        float t4 = fmaxf(acc0[8],  acc0[9]),  t5 = fmaxf(acc0[10], acc0[11]);
        float t6 = fmaxf(acc0[12], acc0[13]), t7 = fmaxf(acc0[14], acc0[15]);
        float u0 = fmaxf(acc1[0],  acc1[1]),  u1 = fmaxf(acc1[2],  acc1[3]);
        float u2 = fmaxf(acc1[4],  acc1[5]),  u3 = fmaxf(acc1[6],  acc1[7]);
        float u4 = fmaxf(acc1[8],  acc1[9]),  u5 = fmaxf(acc1[10], acc1[11]);
        float u6 = fmaxf(acc1[12], acc1[13]), u7 = fmaxf(acc1[14], acc1[15]);
        float ta = fmaxf(fmaxf(fmaxf(t0, t1), fmaxf(t2, t3)),
                         fmaxf(fmaxf(t4, t5), fmaxf(t6, t7)));
        float tb = fmaxf(fmaxf(fmaxf(u0, u1), fmaxf(u2, u3)),
                         fmaxf(fmaxf(u4, u5), fmaxf(u6, u7)));
        float tm = fmaxf(ta, tb);
        tm = fmaxf(tm, __shfl_xor(tm, 32));
        if (!__all(tm <= m + 8.f)) {
            float mn   = fmaxf(m, tm);
            float corr = EXP2F(m - mn);
            m = mn; lsum *= corr;
            #pragma unroll
            for (int dt = 0; dt < 4; ++dt)
                #pragma unroll
                for (int r = 0; r < 16; ++r) o[dt][r] *= corr;
        }
        #pragma unroll
        for (int r = 0; r < 16; ++r) acc0[r] = EXP2F(acc0[r] - m);
        #pragma unroll
        for (int r = 0; r < 16; ++r) acc1[r] = EXP2F(acc1[r] - m);
        float s0 = ((acc0[0]+acc0[1])+(acc0[2]+acc0[3]))
                 + ((acc0[4]+acc0[5])+(acc0[6]+acc0[7]));
        float s1 = ((acc0[8]+acc0[9])+(acc0[10]+acc0[11]))
                 + ((acc0[12]+acc0[13])+(acc0[14]+acc0[15]));
        float s2 = ((acc1[0]+acc1[1])+(acc1[2]+acc1[3]))
                 + ((acc1[4]+acc1[5])+(acc1[6]+acc1[7]));
        float s3 = ((acc1[8]+acc1[9])+(acc1[10]+acc1[11]))
                 + ((acc1[12]+acc1[13])+(acc1[14]+acc1[15]));
        float ps = (s0 + s1) + (s2 + s3);
        ps += __shfl_xor(ps, 32);
        lsum += ps;

        // ---- P -> bf16 PV B-fragments (distinct SSA defs -> permlane safe) --
        short8 pf[4];
        #pragma unroll
        for (int kc = 0; kc < 4; ++kc) {
            const f32x16& a = (kc < 2) ? acc0 : acc1;
            int c1 = (kc & 1) * 8;
            uint W0 = cvtpk(a[c1 + 0], a[c1 + 1]);
            uint W1 = cvtpk(a[c1 + 2], a[c1 + 3]);
            uint W2 = cvtpk(a[c1 + 4], a[c1 + 5]);
            uint W3 = cvtpk(a[c1 + 6], a[c1 + 7]);
            asm("v_permlane32_swap_b32 %0, %1" : "+v"(W0), "+v"(W2));
            asm("v_permlane32_swap_b32 %0, %1" : "+v"(W1), "+v"(W3));
            uint4v pw;
            pw.x = W0; pw.y = W1; pw.z = W2; pw.w = W3;
            pf[kc] = *reinterpret_cast<short8*>(&pw);
        }

        // ---- O^T += V^T P^T, depth-1-step (2-read) prefetch pipeline ----
        // Linear order i = kc*4+dt; reads for step s+1 issued before the two
        // MFMAs of step s (reads are independent of pf).
        short8 vf[2][2];
        {
            int co0 = ((0 * 2 + hi) ^ (q & 7)) * 16;     // kc=0 for i=0,1
            vf[0][0] = *(const short8*)(Vh + (0 * 32 + q) * 128 + co0);
            vf[0][1] = *(const short8*)(Vh + (1 * 32 + q) * 128 + co0);
        }
        __builtin_amdgcn_s_setprio(1);
        #pragma unroll
        for (int s = 0; s < 8; ++s) {
            if (s < 7) {
                int i0 = 2 * s + 2, i1 = 2 * s + 3;
                int coA = (((i0 >> 2) * 2 + hi) ^ (q & 7)) * 16;
                int coB = (((i1 >> 2) * 2 + hi) ^ (q & 7)) * 16;
                vf[(s + 1) & 1][0] = *(const short8*)(Vh + ((i0 & 3) * 32 + q) * 128 + coA);
                vf[(s + 1) & 1][1] = *(const short8*)(Vh + ((i1 & 3) * 32 + q) * 128 + coB);
            }
            o[(2 * s) & 3] = __builtin_amdgcn_mfma_f32_32x32x16_bf16(
                vf[s & 1][0], pf[(2 * s) >> 2], o[(2 * s) & 3], 0, 0, 0);
            o[(2 * s + 1) & 3] = __builtin_amdgcn_mfma_f32_32x32x16_bf16(
                vf[s & 1][1], pf[(2 * s + 1) >> 2], o[(2 * s + 1) & 3], 0, 0, 0);
        }
        __builtin_amdgcn_s_setprio(0);

        __syncthreads();     // reads of buf[cur] done + DMA into buf[cur^1] drained
        cur ^= 1;
    }

    // ---- merge halves through LDS, residual-fused transposed writeout ----
    if (half == 1) {
        float* obuf = (float*)(smem + ww * 16384);
        #pragma unroll
        for (int dt = 0; dt < 4; ++dt)
            #pragma unroll
            for (int r = 0; r < 16; ++r) {
                int dl = dt * 32 + (r & 3) + 8 * (r >> 2) + 4 * hi;
                obuf[dl * 32 + q] = o[dt][r];
            }
        if (hi == 0) {
            float* ml = (float*)(smem + 65536 + ww * 256);
            ml[q * 2]     = m;
            ml[q * 2 + 1] = lsum;
        }
    }
    __syncthreads();
    if (half == 0) {
        const float* obuf = (const float*)(smem + ww * 16384);
        const float* ml   = (const float*)(smem + 65536 + ww * 256);
        float m2 = ml[q * 2], l2 = ml[q * 2 + 1];
        float M  = fmaxf(m, m2);
        float c1 = EXP2F(m - M), c2 = EXP2F(m2 - M);
        float inv = 1.0f / (lsum * c1 + l2 * c2);
        const float* xb = x   + (size_t)b * D_ * S_;
        float*       ob = out + (size_t)b * D_ * S_;
        int s = q0 + ww * 32 + q;
        #pragma unroll
        for (int dt = 0; dt < 4; ++dt)
            #pragma unroll
            for (int r = 0; r < 16; ++r) {
                int dl = dt * 32 + (r & 3) + 8 * (r >> 2) + 4 * hi;
                float val = (o[dt][r] * c1 + obuf[dl * 32 + q] * c2) * inv;
                size_t g = (size_t)dl * S_ + s;
                ob[g] = xb[g] + val;
            }
    }
}

extern "C" void kernel_launch(void* const* d_in, const int* in_sizes, int n_in,
                              void* d_out, int out_size, void* d_ws, size_t ws_size,
                              hipStream_t stream) {
    const float* x  = (const float*)d_in[0];
    const float* Wq = (const float*)d_in[1];
    const float* bq = (const float*)d_in[2];
    const float* Wk = (const float*)d_in[3];
    const float* bk = (const float*)d_in[4];
    const float* Wv = (const float*)d_in[5];
    const float* bv = (const float*)d_in[6];
    float* out = (float*)d_out;

    size_t n = (size_t)B_ * S_ * D_;
    short* Qw = (short*)d_ws;
    short* Kw = Qw + n;
    short* Vw = Kw + n;
    short* Wf = (short*)d_out;   // scratch at head of d_out; fully overwritten

    wpack_kernel<<<24, 256, 0, stream>>>(Wq, Wk, Wv, Wf);

    dim3 grid(S_ / 64, B_);
    qkv_kernel<<<grid, 256, 0, stream>>>(x, Wf, bq, bk, bv, Qw, Kw, Vw);

    int smemB = 131072;
    (void)hipFuncSetAttribute((const void*)attn_kernel,
                              hipFuncAttributeMaxDynamicSharedMemorySize, smemB);
    attn_kernel<<<256, 512, smemB, stream>>>(Qw, Kw, Vw, x, out);
}

// Round 9
// 118.285 us; speedup vs baseline: 1.2021x; 1.0231x over previous
//
#include <hip/hip_runtime.h>
#include <hip/hip_bf16.h>

#define B_ 8
#define D_ 128
#define S_ 4096

typedef short short8 __attribute__((ext_vector_type(8)));
typedef float f32x4  __attribute__((ext_vector_type(4)));
typedef float f32x16 __attribute__((ext_vector_type(16)));
typedef unsigned int uint;
typedef uint uint4v __attribute__((ext_vector_type(4)));

#define EXP2F(x) exp2f(x)

__device__ __forceinline__ short f2bf(float f) {
    __hip_bfloat16 h = __float2bfloat16(f);
    return *reinterpret_cast<short*>(&h);
}

// pack two f32 -> one u32 of 2 bf16 (elem0 = lo word)
__device__ __forceinline__ uint cvtpk(float lo, float hi) {
    uint r;
    asm("v_cvt_pk_bf16_f32 %0, %1, %2" : "=v"(r) : "v"(lo), "v"(hi));
    return r;
}

// async global->LDS DMA, 16B/lane; LDS dest = wave-uniform base + lane*16
__device__ __forceinline__ void gload16(const void* g, void* l) {
    __builtin_amdgcn_global_load_lds(
        (const __attribute__((address_space(1))) void*)g,
        (__attribute__((address_space(3))) void*)l, 16, 0, 0);
}

__device__ __forceinline__ float max3f(float a, float b, float c) {
    return fmaxf(fmaxf(a, b), c);    // clang fuses to v_max3_f32
}

// ---------------------------------------------------------------------------
// Kernel 0: pack Wq/Wk/Wv into bf16 MFMA fragments (16x16x32 layout for qkv).
// ---------------------------------------------------------------------------
__global__ __launch_bounds__(256) void wpack_kernel(
    const float* __restrict__ Wq, const float* __restrict__ Wk,
    const float* __restrict__ Wv, short* __restrict__ Wf)
{
    int g = blockIdx.x * 256 + threadIdx.x;      // 0..6143
    int lane = g & 63, kc = (g >> 6) & 3, n = (g >> 8) & 7, wm = g >> 11;
    const float* W = (wm == 0) ? Wq : (wm == 1) ? Wk : Wv;
    int row = n * 16 + (lane & 15);
    int col = kc * 32 + (lane >> 4) * 8;
    short8 o;
    #pragma unroll
    for (int j = 0; j < 8; ++j) o[j] = f2bf(W[row * 128 + col + j]);
    *((short8*)Wf + g) = o;
}

// ---------------------------------------------------------------------------
// Kernel 1: QKV projection via bf16 MFMA (16x16x32), unchanged.
// Q: (B,S,D) bf16 scaled by log2(e)/sqrt(D). K: (B,S,D). V: (B,D,S).
// ---------------------------------------------------------------------------
__global__ __launch_bounds__(256) void qkv_kernel(
    const float* __restrict__ x, const short* __restrict__ Wf,
    const float* __restrict__ bq, const float* __restrict__ bk,
    const float* __restrict__ bv,
    short* __restrict__ Qo, short* __restrict__ Ko, short* __restrict__ Vo)
{
    __shared__ float xt[64 * 132];
    const int b  = blockIdx.y;
    const int s0 = blockIdx.x * 64;
    const int t  = threadIdx.x;
    const int w    = t >> 6;
    const int lane = t & 63;
    const int lr   = lane & 15;
    const int lg   = lane >> 4;

    const float* xb = x + (size_t)b * D_ * S_;
    #pragma unroll
    for (int it = 0; it < 32; ++it) {
        int d = it * 4 + (t >> 6);
        int s = t & 63;
        xt[s * 132 + d] = xb[(size_t)d * S_ + s0 + s];
    }
    __syncthreads();

    short8 xtf[4];
    {
        const float* base = &xt[(w * 16 + lr) * 132 + lg * 8];
        #pragma unroll
        for (int kc = 0; kc < 4; ++kc) {
            float4 a = *(const float4*)(base + kc * 32);
            float4 c = *(const float4*)(base + kc * 32 + 4);
            short8 f;
            f[0] = f2bf(a.x); f[1] = f2bf(a.y); f[2] = f2bf(a.z); f[3] = f2bf(a.w);
            f[4] = f2bf(c.x); f[5] = f2bf(c.y); f[6] = f2bf(c.z); f[7] = f2bf(c.w);
            xtf[kc] = f;
        }
    }

    const float qs = 0.08838834764831845f * 1.4426950408889634f;
    const short8* W8 = (const short8*)Wf;
    const size_t bSD = (size_t)b * S_ * D_;
    const size_t bDS = (size_t)b * D_ * S_;

    #pragma unroll
    for (int n = 0; n < 8; ++n) {
        f32x4 aq = (f32x4){0.f, 0.f, 0.f, 0.f};
        f32x4 ak = (f32x4){0.f, 0.f, 0.f, 0.f};
        f32x4 av = (f32x4){0.f, 0.f, 0.f, 0.f};
        #pragma unroll
        for (int kc = 0; kc < 4; ++kc) {
            short8 wq = W8[(      n * 4 + kc) * 64 + lane];
            short8 wk = W8[(32  + n * 4 + kc) * 64 + lane];
            short8 wv = W8[(64  + n * 4 + kc) * 64 + lane];
            aq = __builtin_amdgcn_mfma_f32_16x16x32_bf16(xtf[kc], wq, aq, 0, 0, 0);
            ak = __builtin_amdgcn_mfma_f32_16x16x32_bf16(xtf[kc], wk, ak, 0, 0, 0);
            av = __builtin_amdgcn_mfma_f32_16x16x32_bf16(wv, xtf[kc], av, 0, 0, 0);
        }
        int e = n * 16 + lr;
        float bqe = bq[e], bke = bk[e];
        #pragma unroll
        for (int r = 0; r < 4; ++r) {
            size_t off = (bSD + (size_t)(s0 + w * 16 + lg * 4 + r) * D_) + e;
            Qo[off] = f2bf((aq[r] + bqe) * qs);
            Ko[off] = f2bf(ak[r] + bke);
        }
        #pragma unroll
        for (int r = 0; r < 4; ++r) {
            int ev = n * 16 + lg * 4 + r;
            Vo[bDS + (size_t)ev * S_ + s0 + w * 16 + lr] = f2bf(av[r] + bv[ev]);
        }
    }
}

// ---------------------------------------------------------------------------
// Kernel 2: flash attention (R8 base: 512 thr, 2 KV-halves x 4 q-strips,
// 64-kv tiles, K+V DMA-staged, dbuf, 1 barrier/tile) with softmax critical
// path shaved: (1) lsum kept lane-partial, single cross-half shfl after the
// loop (exact: both half-lanes share m/corr); (2) sum-tree moved after
// P-pack + V-prefetch so PV starts earlier and sums hide under PV MFMAs;
// (3) depth-2-pair (4-read) rotating prefetch in QK and PV; (4) v_max3 tree.
// C/D layout (m74/m101): col=lane&31, row=(reg&3)+8*(reg>>2)+4*(lane>>5).
// ---------------------------------------------------------------------------
__global__ __launch_bounds__(512, 2) void attn_kernel(
    const short* __restrict__ Q, const short* __restrict__ K,
    const short* __restrict__ Vt, const float* __restrict__ x,
    float* __restrict__ out)
{
    extern __shared__ __align__(16) char smem[];   // 131072 B
    const int lin = blockIdx.x;
    const int b   = lin & 7;            // XCD swizzle: one b per XCD
    const int q0  = (lin >> 3) * 128;
    const int tid  = threadIdx.x;
    const int w    = tid >> 6;
    const int lane = tid & 63;
    const int q    = lane & 31;         // this lane's q column
    const int hi   = lane >> 5;
    const int half = w >> 2;            // KV half: kt 0..31 -> rows half*2048..
    const int ww   = w & 3;             // q strip (q0 + ww*32 ..)

    const size_t bSD = (size_t)b * S_ * D_;

    // Q fragments: qf[c][j] = Q[q0+ww*32+q][c*16 + hi*8 + j]
    short8 qf[8];
    {
        const short* Qrow = Q + bSD + (size_t)(q0 + ww * 32 + q) * D_ + hi * 8;
        #pragma unroll
        for (int c = 0; c < 8; ++c)
            qf[c] = *(const short8*)(Qrow + c * 16);
    }

    f32x16 o[4];
    #pragma unroll
    for (int dt = 0; dt < 4; ++dt)
        #pragma unroll
        for (int i = 0; i < 16; ++i) o[dt][i] = 0.f;
    float m = -1e30f, lsum = 0.f;      // lsum is LANE-PARTIAL until after loop

    const short* Kb = K + bSD;
    const short* Vb = Vt + (size_t)b * D_ * S_;
    const int ktbase = half * 32;

    // DMA-stage one 64-kv tile of this wave's half into buffer `buf`.
    // LDS dest linear; global src pre-swizzled (phys 16B-chunk c of row r
    // holds logical chunk c^(r&7)).
    auto stage = [&](int kt, int buf) {
        const short* Kg = Kb + (size_t)(ktbase + kt) * 64 * D_;
        const short* Vg = Vb + (size_t)(ktbase + kt) * 64;
        char* Kd = smem + buf * 65536 + half * 32768;
        char* Vd = Kd + 16384;
        #pragma unroll
        for (int i = 0; i < 4; ++i) {
            int ki = ww * 4 + i;                 // 1KB chunk: rows 4ki..4ki+3
            int r  = ki * 4 + (lane >> 4);
            gload16(Kg + r * D_ + (((lane & 15) ^ (r & 7)) * 8), Kd + ki * 1024);
        }
        #pragma unroll
        for (int i = 0; i < 4; ++i) {
            int vi = ww * 4 + i;                 // 1KB chunk: rows 8vi..8vi+7
            int r  = vi * 8 + (lane >> 3);
            gload16(Vg + (size_t)r * S_ + (((lane & 7) ^ (lane >> 3)) * 8),
                    Vd + vi * 1024);
        }
    };

    stage(0, 0);
    __syncthreads();                 // drains vmcnt -> buf0 ready
    int cur = 0;

    for (int kt = 0; kt < 32; ++kt) {
        if (kt + 1 < 32) stage(kt + 1, cur ^ 1);   // DMA overlaps compute

        const char* Kh = smem + cur * 65536 + half * 32768;
        const char* Vh = Kh + 16384;

        // ---- S^T = K Q^T : acc[n][r] = S[k = n*32+(r&3)+8*(r>>2)+4*hi][q] --
        // Depth-2-pair rotating prefetch (reads for c+2 issued at step c).
        f32x16 acc0, acc1;
        #pragma unroll
        for (int i = 0; i < 16; ++i) { acc0[i] = 0.f; acc1[i] = 0.f; }
        short8 kf[3][2];
        {
            int co0 = ((0 + hi) ^ (q & 7)) * 16;
            int co1 = ((2 + hi) ^ (q & 7)) * 16;
            kf[0][0] = *(const short8*)(Kh + q * 256 + co0);
            kf[0][1] = *(const short8*)(Kh + (32 + q) * 256 + co0);
            kf[1][0] = *(const short8*)(Kh + q * 256 + co1);
            kf[1][1] = *(const short8*)(Kh + (32 + q) * 256 + co1);
        }
        __builtin_amdgcn_s_setprio(1);
        #pragma unroll
        for (int c = 0; c < 8; ++c) {
            if (c < 6) {
                int co = (((c + 2) * 2 + hi) ^ (q & 7)) * 16;
                kf[(c + 2) % 3][0] = *(const short8*)(Kh + q * 256 + co);
                kf[(c + 2) % 3][1] = *(const short8*)(Kh + (32 + q) * 256 + co);
            }
            acc0 = __builtin_amdgcn_mfma_f32_32x32x16_bf16(kf[c % 3][0], qf[c], acc0, 0, 0, 0);
            acc1 = __builtin_amdgcn_mfma_f32_32x32x16_bf16(kf[c % 3][1], qf[c], acc1, 0, 0, 0);
        }
        __builtin_amdgcn_s_setprio(0);

        // ---- tile max: 3-ary tree (v_max3), then cross-half, T13 gate ----
        float a0 = max3f(acc0[0],  acc0[1],  acc0[2]);
        float a1 = max3f(acc0[3],  acc0[4],  acc0[5]);
        float a2 = max3f(acc0[6],  acc0[7],  acc0[8]);
        float a3 = max3f(acc0[9],  acc0[10], acc0[11]);
        float a4 = max3f(acc0[12], acc0[13], acc0[14]);
        float a5 = max3f(acc1[0],  acc1[1],  acc1[2]);
        float a6 = max3f(acc1[3],  acc1[4],  acc1[5]);
        float a7 = max3f(acc1[6],  acc1[7],  acc1[8]);
        float a8 = max3f(acc1[9],  acc1[10], acc1[11]);
        float a9 = max3f(acc1[12], acc1[13], acc1[14]);
        float b0 = max3f(a0, a1, a2);
        float b1 = max3f(a3, a4, acc0[15]);
        float b2 = max3f(a5, a6, a7);
        float b3 = max3f(a8, a9, acc1[15]);
        float tm = fmaxf(max3f(b0, b1, b2), b3);
        tm = fmaxf(tm, __shfl_xor(tm, 32));
        if (!__all(tm <= m + 8.f)) {
            float mn   = fmaxf(m, tm);
            float corr = EXP2F(m - mn);
            m = mn; lsum *= corr;
            #pragma unroll
            for (int dt = 0; dt < 4; ++dt)
                #pragma unroll
                for (int r = 0; r < 16; ++r) o[dt][r] *= corr;
        }
        #pragma unroll
        for (int r = 0; r < 16; ++r) acc0[r] = EXP2F(acc0[r] - m);
        #pragma unroll
        for (int r = 0; r < 16; ++r) acc1[r] = EXP2F(acc1[r] - m);

        // ---- P -> bf16 PV B-fragments (distinct SSA defs -> permlane safe) --
        short8 pf[4];
        #pragma unroll
        for (int kc = 0; kc < 4; ++kc) {
            const f32x16& a = (kc < 2) ? acc0 : acc1;
            int c1 = (kc & 1) * 8;
            uint W0 = cvtpk(a[c1 + 0], a[c1 + 1]);
            uint W1 = cvtpk(a[c1 + 2], a[c1 + 3]);
            uint W2 = cvtpk(a[c1 + 4], a[c1 + 5]);
            uint W3 = cvtpk(a[c1 + 6], a[c1 + 7]);
            asm("v_permlane32_swap_b32 %0, %1" : "+v"(W0), "+v"(W2));
            asm("v_permlane32_swap_b32 %0, %1" : "+v"(W1), "+v"(W3));
            uint4v pw;
            pw.x = W0; pw.y = W1; pw.z = W2; pw.w = W3;
            pf[kc] = *reinterpret_cast<short8*>(&pw);
        }

        // ---- V prefetch (2 pairs), then sums (hide under PV), then PV ----
        short8 vf[3][2];
        {
            int co0 = ((0 + hi) ^ (q & 7)) * 16;     // kc=0 for i=0,1
            vf[0][0] = *(const short8*)(Vh + (0 * 32 + q) * 128 + co0);
            vf[0][1] = *(const short8*)(Vh + (1 * 32 + q) * 128 + co0);
            vf[1][0] = *(const short8*)(Vh + (2 * 32 + q) * 128 + co0);
            vf[1][1] = *(const short8*)(Vh + (3 * 32 + q) * 128 + co0);
        }
        // lane-partial sum tree (cross-half shfl deferred to after the loop)
        float s0 = ((acc0[0]+acc0[1])+(acc0[2]+acc0[3]))
                 + ((acc0[4]+acc0[5])+(acc0[6]+acc0[7]));
        float s1 = ((acc0[8]+acc0[9])+(acc0[10]+acc0[11]))
                 + ((acc0[12]+acc0[13])+(acc0[14]+acc0[15]));
        float s2 = ((acc1[0]+acc1[1])+(acc1[2]+acc1[3]))
                 + ((acc1[4]+acc1[5])+(acc1[6]+acc1[7]));
        float s3 = ((acc1[8]+acc1[9])+(acc1[10]+acc1[11]))
                 + ((acc1[12]+acc1[13])+(acc1[14]+acc1[15]));
        lsum += (s0 + s1) + (s2 + s3);

        // ---- O^T += V^T P^T, rotating prefetch (2 read-pairs in flight) ----
        // Linear order i = kc*4+dt: vf for step s+2 issued at step s.
        __builtin_amdgcn_s_setprio(1);
        #pragma unroll
        for (int s = 0; s < 8; ++s) {
            if (s < 6) {
                int i0 = 2 * s + 4, i1 = 2 * s + 5;
                int coA = (((i0 >> 2) * 2 + hi) ^ (q & 7)) * 16;
                int coB = (((i1 >> 2) * 2 + hi) ^ (q & 7)) * 16;
                vf[(s + 2) % 3][0] = *(const short8*)(Vh + ((i0 & 3) * 32 + q) * 128 + coA);
                vf[(s + 2) % 3][1] = *(const short8*)(Vh + ((i1 & 3) * 32 + q) * 128 + coB);
            }
            o[(2 * s) & 3] = __builtin_amdgcn_mfma_f32_32x32x16_bf16(
                vf[s % 3][0], pf[(2 * s) >> 2], o[(2 * s) & 3], 0, 0, 0);
            o[(2 * s + 1) & 3] = __builtin_amdgcn_mfma_f32_32x32x16_bf16(
                vf[s % 3][1], pf[(2 * s + 1) >> 2], o[(2 * s + 1) & 3], 0, 0, 0);
        }
        __builtin_amdgcn_s_setprio(0);

        __syncthreads();     // reads of buf[cur] done + DMA into buf[cur^1] drained
        cur ^= 1;
    }

    // Complete the cross-half lsum reduction once (exact: see header comment).
    lsum += __shfl_xor(lsum, 32);

    // ---- merge halves through LDS, residual-fused transposed writeout ----
    if (half == 1) {
        float* obuf = (float*)(smem + ww * 16384);
        #pragma unroll
        for (int dt = 0; dt < 4; ++dt)
            #pragma unroll
            for (int r = 0; r < 16; ++r) {
                int dl = dt * 32 + (r & 3) + 8 * (r >> 2) + 4 * hi;
                obuf[dl * 32 + q] = o[dt][r];
            }
        if (hi == 0) {
            float* ml = (float*)(smem + 65536 + ww * 256);
            ml[q * 2]     = m;
            ml[q * 2 + 1] = lsum;
        }
    }
    __syncthreads();
    if (half == 0) {
        const float* obuf = (const float*)(smem + ww * 16384);
        const float* ml   = (const float*)(smem + 65536 + ww * 256);
        float m2 = ml[q * 2], l2 = ml[q * 2 + 1];
        float M  = fmaxf(m, m2);
        float c1 = EXP2F(m - M), c2 = EXP2F(m2 - M);
        float inv = 1.0f / (lsum * c1 + l2 * c2);
        const float* xb = x   + (size_t)b * D_ * S_;
        float*       ob = out + (size_t)b * D_ * S_;
        int s = q0 + ww * 32 + q;
        #pragma unroll
        for (int dt = 0; dt < 4; ++dt)
            #pragma unroll
            for (int r = 0; r < 16; ++r) {
                int dl = dt * 32 + (r & 3) + 8 * (r >> 2) + 4 * hi;
                float val = (o[dt][r] * c1 + obuf[dl * 32 + q] * c2) * inv;
                size_t g = (size_t)dl * S_ + s;
                ob[g] = xb[g] + val;
            }
    }
}

extern "C" void kernel_launch(void* const* d_in, const int* in_sizes, int n_in,
                              void* d_out, int out_size, void* d_ws, size_t ws_size,
                              hipStream_t stream) {
    const float* x  = (const float*)d_in[0];
    const float* Wq = (const float*)d_in[1];
    const float* bq = (const float*)d_in[2];
    const float* Wk = (const float*)d_in[3];
    const float* bk = (const float*)d_in[4];
    const float* Wv = (const float*)d_in[5];
    const float* bv = (const float*)d_in[6];
    float* out = (float*)d_out;

    size_t n = (size_t)B_ * S_ * D_;
    short* Qw = (short*)d_ws;
    short* Kw = Qw + n;
    short* Vw = Kw + n;
    short* Wf = (short*)d_out;   // scratch at head of d_out; fully overwritten

    wpack_kernel<<<24, 256, 0, stream>>>(Wq, Wk, Wv, Wf);

    dim3 grid(S_ / 64, B_);
    qkv_kernel<<<grid, 256, 0, stream>>>(x, Wf, bq, bk, bv, Qw, Kw, Vw);

    int smemB = 131072;
    (void)hipFuncSetAttribute((const void*)attn_kernel,
                              hipFuncAttributeMaxDynamicSharedMemorySize, smemB);
    attn_kernel<<<256, 512, smemB, stream>>>(Qw, Kw, Vw, x, out);
}